// Round 1
// baseline (230.463 us; speedup 1.0000x reference)
//
#include <hip/hip_runtime.h>
#include <math.h>

// ---------------------------------------------------------------------------
// ClusterML pipeline:
//   1) out = x @ W.T + b                (bf16 MFMA, fp32 in/out)   [131072,128]
//   2) per-class partial sums/counts    (LDS atomics, 256 blocks)
//   3) reduce partials -> sums          (32 blocks)
//   4) centroids = c0 + sums/cnt, norms (1 block)
//   5) proto_dist (64x64)               (16 blocks)
//   6) dist(out, cent) -> sigmoid(exp)  (bf16 MFMA)                [131072,64]
//
// ws layout (fp32 elems): out[131072*128] | pw[256*8192] | pc[256*64]
//                         | sums[8192] | cent[8192] | cnorm[64]  (~72.2 MB)
// ---------------------------------------------------------------------------

typedef __bf16 bf16;
typedef bf16  bf16x4 __attribute__((ext_vector_type(4)));
typedef bf16  bf16x8 __attribute__((ext_vector_type(8)));
typedef float f32x4  __attribute__((ext_vector_type(4)));

#define B_ROWS 131072
#define K_DIM  512
#define E_DIM  128
#define C_CLS  64

#define BM 128
#define BN 128
#define BK 64

#define SEG_BLOCKS 256
#define ROWS_PER_SEG (B_ROWS / SEG_BLOCKS)   // 512

// -------------------- Kernel 1: out = x @ W^T + bias -----------------------
__global__ __launch_bounds__(256, 2)
void gemm_kernel(const float* __restrict__ x, const float* __restrict__ W,
                 const float* __restrict__ bias, float* __restrict__ out)
{
    __shared__ bf16 As[BM * BK];   // [128][64] bf16, XOR-swizzled rows
    __shared__ bf16 Bs[BN * BK];

    const int t    = threadIdx.x;
    const int lane = t & 63;
    const int w    = t >> 6;        // wave 0..3
    const int wr   = w >> 1;        // 0..1 (M half)
    const int wc   = w & 1;         // 0..1 (N half)
    const int fr   = lane & 15;
    const int fq   = lane >> 4;
    const long blockRow = (long)blockIdx.x * BM;

    const int srow = t >> 4;        // 0..15 staging row-in-round
    const int scol = (t & 15) * 4;  // 0..60 staging col (elems)

    f32x4 acc[4][4] = {};

    const float* xg = x + blockRow * K_DIM;

    for (int kt = 0; kt < K_DIM; kt += BK) {
        __syncthreads();
        #pragma unroll
        for (int r = 0; r < 8; ++r) {
            int row = r * 16 + srow;
            f32x4 va = *(const f32x4*)(xg + (long)row * K_DIM + kt + scol);
            f32x4 vb = *(const f32x4*)(W  + (long)row * K_DIM + kt + scol);
            bf16x4 pa = { (bf16)va.x, (bf16)va.y, (bf16)va.z, (bf16)va.w };
            bf16x4 pb = { (bf16)vb.x, (bf16)vb.y, (bf16)vb.z, (bf16)vb.w };
            int byte = row * (BK * 2) + ((scol * 2) ^ ((row & 7) << 4));
            *(bf16x4*)((char*)As + byte) = pa;
            *(bf16x4*)((char*)Bs + byte) = pb;
        }
        __syncthreads();
        #pragma unroll
        for (int kk = 0; kk < 2; ++kk) {
            bf16x8 af[4], bg[4];
            #pragma unroll
            for (int m = 0; m < 4; ++m) {
                int row  = wr * 64 + m * 16 + fr;
                int byte = row * (BK * 2) + (((kk * 32 + fq * 8) * 2) ^ ((row & 7) << 4));
                af[m] = *(const bf16x8*)((const char*)As + byte);
            }
            #pragma unroll
            for (int n = 0; n < 4; ++n) {
                int row  = wc * 64 + n * 16 + fr;
                int byte = row * (BK * 2) + (((kk * 32 + fq * 8) * 2) ^ ((row & 7) << 4));
                bg[n] = *(const bf16x8*)((const char*)Bs + byte);
            }
            #pragma unroll
            for (int m = 0; m < 4; ++m)
                #pragma unroll
                for (int n = 0; n < 4; ++n)
                    acc[m][n] = __builtin_amdgcn_mfma_f32_16x16x32_bf16(
                        af[m], bg[n], acc[m][n], 0, 0, 0);
        }
    }

    // epilogue: C/D layout col = lane&15, row = (lane>>4)*4 + j
    #pragma unroll
    for (int n = 0; n < 4; ++n) {
        int gcol = wc * 64 + n * 16 + fr;
        float bv = bias[gcol];
        #pragma unroll
        for (int m = 0; m < 4; ++m) {
            #pragma unroll
            for (int j = 0; j < 4; ++j) {
                long grow = blockRow + wr * 64 + m * 16 + fq * 4 + j;
                out[grow * E_DIM + gcol] = acc[m][n][j] + bv;
            }
        }
    }
}

// -------------------- Kernel 2: per-class partial sums ---------------------
__global__ __launch_bounds__(256)
void segsum_kernel(const float* __restrict__ out, const int* __restrict__ y,
                   float* __restrict__ pw, float* __restrict__ pc)
{
    __shared__ float lsum[C_CLS * E_DIM];
    __shared__ float lcnt[C_CLS];
    const int t = threadIdx.x;
    for (int i = t; i < C_CLS * E_DIM; i += 256) lsum[i] = 0.f;
    if (t < C_CLS) lcnt[t] = 0.f;
    __syncthreads();
    const long base = (long)blockIdx.x * ROWS_PER_SEG;
    for (int r = t; r < ROWS_PER_SEG; r += 256)
        atomicAdd(&lcnt[y[base + r]], 1.0f);
    const int rsub = t >> 5;          // 0..7
    const int c4   = (t & 31) * 4;    // 0..124
    for (int i = 0; i < ROWS_PER_SEG; i += 8) {
        long row = base + i + rsub;
        int  cls = y[row];
        f32x4 v = *(const f32x4*)(out + row * E_DIM + c4);
        atomicAdd(&lsum[cls * E_DIM + c4 + 0], v.x);
        atomicAdd(&lsum[cls * E_DIM + c4 + 1], v.y);
        atomicAdd(&lsum[cls * E_DIM + c4 + 2], v.z);
        atomicAdd(&lsum[cls * E_DIM + c4 + 3], v.w);
    }
    __syncthreads();
    for (int i = t; i < C_CLS * E_DIM; i += 256)
        pw[(long)blockIdx.x * (C_CLS * E_DIM) + i] = lsum[i];
    if (t < C_CLS) pc[blockIdx.x * C_CLS + t] = lcnt[t];
}

// -------------------- Kernel 3: reduce partials ----------------------------
__global__ __launch_bounds__(256)
void reduce_kernel(const float* __restrict__ pw, float* __restrict__ sums)
{
    int idx = blockIdx.x * 256 + threadIdx.x;   // 0..8191
    float s = 0.f;
    for (int j = 0; j < SEG_BLOCKS; ++j) s += pw[(long)j * (C_CLS * E_DIM) + idx];
    sums[idx] = s;
}

// -------------------- Kernel 4: centroids + norms --------------------------
__global__ __launch_bounds__(256)
void centroid_kernel(const float* __restrict__ sums, const float* __restrict__ pc,
                     const float* __restrict__ centroid0,
                     float* __restrict__ cent, float* __restrict__ cnorm)
{
    __shared__ float cnt[C_CLS];
    __shared__ float sc[C_CLS * E_DIM];
    const int t = threadIdx.x;
    if (t < C_CLS) {
        float s = 0.f;
        for (int j = 0; j < SEG_BLOCKS; ++j) s += pc[j * C_CLS + t];
        cnt[t] = s;
    }
    __syncthreads();
    for (int i = t; i < C_CLS * E_DIM; i += 256) {
        float v = centroid0[i] + sums[i] / cnt[i >> 7];
        sc[i]   = v;
        cent[i] = v;
    }
    __syncthreads();
    if (t < C_CLS) {
        float s = 0.f;
        for (int e = 0; e < E_DIM; ++e) { float v = sc[t * E_DIM + e]; s += v * v; }
        cnorm[t] = s;
    }
}

// -------------------- Kernel 5: proto_dist (64x64) -------------------------
__global__ __launch_bounds__(256)
void proto_kernel(const float* __restrict__ cent, const float* __restrict__ cnorm,
                  float* __restrict__ proto)
{
    __shared__ float sc[C_CLS * E_DIM];
    const int t = threadIdx.x;
    for (int i = t; i < C_CLS * E_DIM; i += 256) sc[i] = cent[i];
    __syncthreads();
    int p = blockIdx.x * 256 + t;    // 0..4095
    int i = p >> 6, j = p & 63;
    float d = 0.f;
    for (int e = 0; e < E_DIM; ++e) d += sc[i * E_DIM + e] * sc[j * E_DIM + e];
    float d2 = cnorm[i] + cnorm[j] - 2.f * d;
    proto[p] = __expf(-0.5f * sqrtf(fmaxf(d2, 1e-12f)));
}

// -------------------- Kernel 6: dist + sigmoid -----------------------------
__global__ __launch_bounds__(256, 4)
void dist_kernel(const float* __restrict__ out, const float* __restrict__ cent,
                 const float* __restrict__ cnorm, float* __restrict__ out0)
{
    __shared__ bf16  Cs[C_CLS * E_DIM];   // [64][128] bf16, XOR-swizzled
    __shared__ float snorm[C_CLS];
    __shared__ float rnorm[128];
    const int t = threadIdx.x;
    {
        int srow = t >> 5;                // 0..7
        int scol = (t & 31) * 4;          // 0..124
        #pragma unroll
        for (int r = 0; r < 8; ++r) {
            int row = r * 8 + srow;
            f32x4 v = *(const f32x4*)(cent + row * E_DIM + scol);
            bf16x4 pv = { (bf16)v.x, (bf16)v.y, (bf16)v.z, (bf16)v.w };
            int byte = row * (E_DIM * 2) + ((scol * 2) ^ ((row & 7) << 4));
            *(bf16x4*)((char*)Cs + byte) = pv;
        }
        if (t < C_CLS) snorm[t] = cnorm[t];
    }
    const int lane = t & 63;
    const int w    = t >> 6;
    const int fr   = lane & 15;
    const int fq   = lane >> 4;
    const long blkrow = (long)blockIdx.x * 128;
    f32x4 acc[2][4] = {};
    float sq0 = 0.f, sq1 = 0.f;
    __syncthreads();
    #pragma unroll
    for (int kt = 0; kt < 4; ++kt) {
        bf16x8 af[2];
        #pragma unroll
        for (int m = 0; m < 2; ++m) {
            long row = blkrow + w * 32 + m * 16 + fr;
            const f32x4* p = (const f32x4*)(out + row * E_DIM + kt * 32 + fq * 8);
            f32x4 v0 = p[0];
            f32x4 v1 = p[1];
            float s = v0.x*v0.x + v0.y*v0.y + v0.z*v0.z + v0.w*v0.w
                    + v1.x*v1.x + v1.y*v1.y + v1.z*v1.z + v1.w*v1.w;
            if (m == 0) sq0 += s; else sq1 += s;
            bf16x8 a;
            a[0]=(bf16)v0.x; a[1]=(bf16)v0.y; a[2]=(bf16)v0.z; a[3]=(bf16)v0.w;
            a[4]=(bf16)v1.x; a[5]=(bf16)v1.y; a[6]=(bf16)v1.z; a[7]=(bf16)v1.w;
            af[m] = a;
        }
        #pragma unroll
        for (int n = 0; n < 4; ++n) {
            int row  = n * 16 + fr;
            int byte = row * (E_DIM * 2) + (((kt * 32 + fq * 8) * 2) ^ ((row & 7) << 4));
            bf16x8 bq = *(const bf16x8*)((const char*)Cs + byte);
            acc[0][n] = __builtin_amdgcn_mfma_f32_16x16x32_bf16(af[0], bq, acc[0][n], 0, 0, 0);
            acc[1][n] = __builtin_amdgcn_mfma_f32_16x16x32_bf16(af[1], bq, acc[1][n], 0, 0, 0);
        }
    }
    // reduce row norms across fq groups (lane bits 4,5)
    sq0 += __shfl_xor(sq0, 16); sq0 += __shfl_xor(sq0, 32);
    sq1 += __shfl_xor(sq1, 16); sq1 += __shfl_xor(sq1, 32);
    if (fq == 0) {
        rnorm[w * 32 + fr]      = sq0;
        rnorm[w * 32 + 16 + fr] = sq1;
    }
    __syncthreads();
    #pragma unroll
    for (int m = 0; m < 2; ++m) {
        #pragma unroll
        for (int n = 0; n < 4; ++n) {
            int gcol = n * 16 + fr;
            float cn = snorm[gcol];
            #pragma unroll
            for (int j = 0; j < 4; ++j) {
                int lrow = w * 32 + m * 16 + fq * 4 + j;
                float d2 = rnorm[lrow] + cn - 2.f * acc[m][n][j];
                float dist = sqrtf(fmaxf(d2, 1e-12f));
                float ez = __expf(-0.5f * dist);
                out0[(blkrow + lrow) * C_CLS + gcol] = 1.f / (1.f + __expf(-ez));
            }
        }
    }
}

// ---------------------------------------------------------------------------
extern "C" void kernel_launch(void* const* d_in, const int* in_sizes, int n_in,
                              void* d_out, int out_size, void* d_ws, size_t ws_size,
                              hipStream_t stream)
{
    const float* x         = (const float*)d_in[0];
    const int*   y         = (const int*)d_in[1];
    const float* W         = (const float*)d_in[2];
    const float* bias      = (const float*)d_in[3];
    const float* centroid0 = (const float*)d_in[4];

    float* outb  = (float*)d_ws;                               // 131072*128
    float* pw    = outb + (long)B_ROWS * E_DIM;                // 256*8192
    float* pc    = pw + (long)SEG_BLOCKS * C_CLS * E_DIM;      // 256*64
    float* sums  = pc + SEG_BLOCKS * C_CLS;                    // 8192
    float* cent  = sums + C_CLS * E_DIM;                       // 8192
    float* cnorm = cent + C_CLS * E_DIM;                       // 64

    float* out0  = (float*)d_out;
    float* proto = out0 + (long)B_ROWS * C_CLS;

    gemm_kernel    <<<B_ROWS / BM, 256, 0, stream>>>(x, W, bias, outb);
    segsum_kernel  <<<SEG_BLOCKS, 256, 0, stream>>>(outb, y, pw, pc);
    reduce_kernel  <<<(C_CLS * E_DIM) / 256, 256, 0, stream>>>(pw, sums);
    centroid_kernel<<<1, 256, 0, stream>>>(sums, pc, centroid0, cent, cnorm);
    proto_kernel   <<<(C_CLS * C_CLS) / 256, 256, 0, stream>>>(cent, cnorm, proto);
    dist_kernel    <<<B_ROWS / 128, 256, 0, stream>>>(outb, cent, cnorm, out0);
}

// Round 2
// 192.937 us; speedup vs baseline: 1.1945x; 1.1945x over previous
//
#include <hip/hip_runtime.h>
#include <math.h>

// ---------------------------------------------------------------------------
// ClusterML pipeline (round 2: bf16 out, fused rnorm, fused proto):
//   1) gemm:    out_bf16 = bf16(x @ W.T + b); rnorm[r] = ||out_r||^2 (fp32)
//   2) segsum:  per-class partial sums/counts (LDS atomics, 256 blocks)
//   3) reduce:  partials -> sums (32 blocks)
//   4) centroid: cent = c0 + sums/cnt, cnorm (1 block)
//   5) dist:    blocks [0,1024): sigmoid(exp(-0.5*dist(out,cent)))
//               blocks [1024,1040): proto_dist(cent,cent)
//
// ws (fp32-elem units): outb(bf16 33.5MB) | rnorm 0.5MB | pw 8.4MB | pc | sums
//                       | cent | cnorm   (~43 MB total)
// ---------------------------------------------------------------------------

typedef __bf16 bf16;
typedef bf16  bf16x4 __attribute__((ext_vector_type(4)));
typedef bf16  bf16x8 __attribute__((ext_vector_type(8)));
typedef float f32x4  __attribute__((ext_vector_type(4)));

#define B_ROWS 131072
#define K_DIM  512
#define E_DIM  128
#define C_CLS  64

#define BM 128
#define BK 64

#define SEG_BLOCKS 256
#define ROWS_PER_SEG (B_ROWS / SEG_BLOCKS)   // 512

#define DIST_BLOCKS (B_ROWS / 128)           // 1024
#define PROTO_BLOCKS 16

// -------------------- Kernel 1: out = bf16(x @ W^T + bias), rnorm ----------
__global__ __launch_bounds__(256, 2)
void gemm_kernel(const float* __restrict__ x, const float* __restrict__ W,
                 const float* __restrict__ bias, bf16* __restrict__ outb,
                 float* __restrict__ rnorm)
{
    __shared__ bf16 As[BM * BK];   // [128][64] bf16, XOR-swizzled rows
    __shared__ bf16 Bs[BM * BK];
    __shared__ float lr[BM];

    const int t    = threadIdx.x;
    const int lane = t & 63;
    const int w    = t >> 6;        // wave 0..3
    const int wr   = w >> 1;        // 0..1 (M half)
    const int wc   = w & 1;         // 0..1 (N half)
    const int fr   = lane & 15;
    const int fq   = lane >> 4;
    const long blockRow = (long)blockIdx.x * BM;

    const int srow = t >> 4;        // 0..15 staging row-in-round
    const int scol = (t & 15) * 4;  // 0..60 staging col (elems)

    f32x4 acc[4][4] = {};
    if (t < BM) lr[t] = 0.f;

    const float* xg = x + blockRow * K_DIM;

    for (int kt = 0; kt < K_DIM; kt += BK) {
        __syncthreads();
        #pragma unroll
        for (int r = 0; r < 8; ++r) {
            int row = r * 16 + srow;
            f32x4 va = *(const f32x4*)(xg + (long)row * K_DIM + kt + scol);
            f32x4 vb = *(const f32x4*)(W  + (long)row * K_DIM + kt + scol);
            bf16x4 pa = { (bf16)va.x, (bf16)va.y, (bf16)va.z, (bf16)va.w };
            bf16x4 pb = { (bf16)vb.x, (bf16)vb.y, (bf16)vb.z, (bf16)vb.w };
            int byte = row * (BK * 2) + ((scol * 2) ^ ((row & 7) << 4));
            *(bf16x4*)((char*)As + byte) = pa;
            *(bf16x4*)((char*)Bs + byte) = pb;
        }
        __syncthreads();
        #pragma unroll
        for (int kk = 0; kk < 2; ++kk) {
            bf16x8 af[4], bg[4];
            #pragma unroll
            for (int m = 0; m < 4; ++m) {
                int row  = wr * 64 + m * 16 + fr;
                int byte = row * (BK * 2) + (((kk * 32 + fq * 8) * 2) ^ ((row & 7) << 4));
                af[m] = *(const bf16x8*)((const char*)As + byte);
            }
            #pragma unroll
            for (int n = 0; n < 4; ++n) {
                int row  = wc * 64 + n * 16 + fr;
                int byte = row * (BK * 2) + (((kk * 32 + fq * 8) * 2) ^ ((row & 7) << 4));
                bg[n] = *(const bf16x8*)((const char*)Bs + byte);
            }
            #pragma unroll
            for (int m = 0; m < 4; ++m)
                #pragma unroll
                for (int n = 0; n < 4; ++n)
                    acc[m][n] = __builtin_amdgcn_mfma_f32_16x16x32_bf16(
                        af[m], bg[n], acc[m][n], 0, 0, 0);
        }
    }

    // epilogue: C/D layout col = lane&15, row = (lane>>4)*4 + j
    float bvv[4];
    #pragma unroll
    for (int n = 0; n < 4; ++n) bvv[n] = bias[wc * 64 + n * 16 + fr];

    #pragma unroll
    for (int m = 0; m < 4; ++m) {
        #pragma unroll
        for (int j = 0; j < 4; ++j) {
            long grow = blockRow + wr * 64 + m * 16 + fq * 4 + j;
            float s = 0.f;
            #pragma unroll
            for (int n = 0; n < 4; ++n) {
                float v = acc[m][n][j] + bvv[n];
                outb[grow * E_DIM + wc * 64 + n * 16 + fr] = (bf16)v;
                s += v * v;
            }
            // reduce across fr (lane bits 0..3): 16 cols -> this wave's half-row
            s += __shfl_xor(s, 1); s += __shfl_xor(s, 2);
            s += __shfl_xor(s, 4); s += __shfl_xor(s, 8);
            if (fr == 0) atomicAdd(&lr[wr * 64 + m * 16 + fq * 4 + j], s);
        }
    }
    __syncthreads();
    if (t < BM) rnorm[blockRow + t] = lr[t];
}

// -------------------- Kernel 2: per-class partial sums ---------------------
__global__ __launch_bounds__(256)
void segsum_kernel(const bf16* __restrict__ outb, const int* __restrict__ y,
                   float* __restrict__ pw, float* __restrict__ pc)
{
    __shared__ float lsum[C_CLS * E_DIM];
    __shared__ float lcnt[C_CLS];
    const int t = threadIdx.x;
    for (int i = t; i < C_CLS * E_DIM; i += 256) lsum[i] = 0.f;
    if (t < C_CLS) lcnt[t] = 0.f;
    __syncthreads();
    const long base = (long)blockIdx.x * ROWS_PER_SEG;
    const int rsub = t >> 4;          // 0..15 rows per pass
    const int c8   = (t & 15) * 8;    // 0..120
    for (int i = 0; i < ROWS_PER_SEG; i += 16) {
        long row = base + i + rsub;
        int  cls = y[row];
        bf16x8 v = *(const bf16x8*)(outb + row * E_DIM + c8);
        if ((t & 15) == 0) atomicAdd(&lcnt[cls], 1.0f);
        #pragma unroll
        for (int k = 0; k < 8; ++k)
            atomicAdd(&lsum[cls * E_DIM + c8 + k], (float)v[k]);
    }
    __syncthreads();
    for (int i = t; i < C_CLS * E_DIM; i += 256)
        pw[(long)blockIdx.x * (C_CLS * E_DIM) + i] = lsum[i];
    if (t < C_CLS) pc[blockIdx.x * C_CLS + t] = lcnt[t];
}

// -------------------- Kernel 3: reduce partials ----------------------------
__global__ __launch_bounds__(256)
void reduce_kernel(const float* __restrict__ pw, float* __restrict__ sums)
{
    int idx = blockIdx.x * 256 + threadIdx.x;   // 0..8191
    float s = 0.f;
    for (int j = 0; j < SEG_BLOCKS; ++j) s += pw[(long)j * (C_CLS * E_DIM) + idx];
    sums[idx] = s;
}

// -------------------- Kernel 4: centroids + norms --------------------------
__global__ __launch_bounds__(256)
void centroid_kernel(const float* __restrict__ sums, const float* __restrict__ pc,
                     const float* __restrict__ centroid0,
                     float* __restrict__ cent, float* __restrict__ cnorm)
{
    __shared__ float cnt[C_CLS];
    __shared__ float sc[C_CLS * E_DIM];
    const int t = threadIdx.x;
    if (t < C_CLS) {
        float s = 0.f;
        for (int j = 0; j < SEG_BLOCKS; ++j) s += pc[j * C_CLS + t];
        cnt[t] = s;
    }
    __syncthreads();
    for (int i = t; i < C_CLS * E_DIM; i += 256) {
        float v = centroid0[i] + sums[i] / cnt[i >> 7];
        sc[i]   = v;
        cent[i] = v;
    }
    __syncthreads();
    if (t < C_CLS) {
        float s = 0.f;
        for (int e = 0; e < E_DIM; ++e) { float v = sc[t * E_DIM + e]; s += v * v; }
        cnorm[t] = s;
    }
}

// -------------------- Kernel 5: dist + sigmoid (+ fused proto) -------------
__global__ __launch_bounds__(256, 4)
void dist_kernel(const bf16* __restrict__ outb, const float* __restrict__ cent,
                 const float* __restrict__ cnorm, const float* __restrict__ rnorm,
                 float* __restrict__ out0, float* __restrict__ proto)
{
    // union LDS: dist uses Cs(bf16 16KB)+snorm+srnorm; proto uses scf(f32, 129-
    // stride, 33KB)+pnorm
    __shared__ float smemf[C_CLS * 129 + C_CLS + 128];
    const int t = threadIdx.x;

    if (blockIdx.x >= DIST_BLOCKS) {
        // ---- proto path: 16 blocks x 256 threads = 4096 outputs ----
        float* scf   = smemf;                    // [64][129]
        float* pnorm = smemf + C_CLS * 129;
        for (int idx = t; idx < C_CLS * E_DIM; idx += 256)
            scf[(idx >> 7) * 129 + (idx & 127)] = cent[idx];
        if (t < C_CLS) pnorm[t] = cnorm[t];
        __syncthreads();
        int p = (blockIdx.x - DIST_BLOCKS) * 256 + t;  // 0..4095
        int i = p >> 6, j = p & 63;                    // i wave-uniform, j=lane
        float d = 0.f;
        #pragma unroll 4
        for (int e = 0; e < E_DIM; ++e)
            d += scf[i * 129 + e] * scf[j * 129 + e];
        float d2 = pnorm[i] + pnorm[j] - 2.f * d;
        proto[p] = __expf(-0.5f * sqrtf(fmaxf(d2, 1e-12f)));
        return;
    }

    bf16*  Cs    = (bf16*)smemf;                 // [64][128] bf16, XOR-swizzled
    float* snorm = smemf + C_CLS * 129;          // [64]
    float* srnorm = snorm + C_CLS;               // [128]
    {
        int srw = t >> 5;                 // 0..7
        int scl = (t & 31) * 4;           // 0..124
        #pragma unroll
        for (int r = 0; r < 8; ++r) {
            int row = r * 8 + srw;
            f32x4 v = *(const f32x4*)(cent + row * E_DIM + scl);
            bf16x4 pv = { (bf16)v.x, (bf16)v.y, (bf16)v.z, (bf16)v.w };
            int byte = row * (E_DIM * 2) + ((scl * 2) ^ ((row & 7) << 4));
            *(bf16x4*)((char*)Cs + byte) = pv;
        }
        if (t < C_CLS) snorm[t] = cnorm[t];
        if (t < 32) ((f32x4*)srnorm)[t] =
            ((const f32x4*)(rnorm + (long)blockIdx.x * 128))[t];
    }
    const int lane = t & 63;
    const int w    = t >> 6;
    const int fr   = lane & 15;
    const int fq   = lane >> 4;
    const long blkrow = (long)blockIdx.x * 128;
    f32x4 acc[2][4] = {};
    __syncthreads();
    #pragma unroll
    for (int kt = 0; kt < 4; ++kt) {
        bf16x8 af[2];
        #pragma unroll
        for (int m = 0; m < 2; ++m) {
            long row = blkrow + w * 32 + m * 16 + fr;
            af[m] = *(const bf16x8*)(outb + row * E_DIM + kt * 32 + fq * 8);
        }
        #pragma unroll
        for (int n = 0; n < 4; ++n) {
            int row  = n * 16 + fr;
            int byte = row * (E_DIM * 2) + (((kt * 32 + fq * 8) * 2) ^ ((row & 7) << 4));
            bf16x8 bq = *(const bf16x8*)((const char*)Cs + byte);
            acc[0][n] = __builtin_amdgcn_mfma_f32_16x16x32_bf16(af[0], bq, acc[0][n], 0, 0, 0);
            acc[1][n] = __builtin_amdgcn_mfma_f32_16x16x32_bf16(af[1], bq, acc[1][n], 0, 0, 0);
        }
    }
    #pragma unroll
    for (int m = 0; m < 2; ++m) {
        #pragma unroll
        for (int n = 0; n < 4; ++n) {
            int gcol = n * 16 + fr;
            float cn = snorm[gcol];
            #pragma unroll
            for (int j = 0; j < 4; ++j) {
                int lrow = w * 32 + m * 16 + fq * 4 + j;
                float d2 = srnorm[lrow] + cn - 2.f * acc[m][n][j];
                float dist = sqrtf(fmaxf(d2, 1e-12f));
                float ez = __expf(-0.5f * dist);
                out0[(blkrow + lrow) * C_CLS + gcol] = 1.f / (1.f + __expf(-ez));
            }
        }
    }
}

// ---------------------------------------------------------------------------
extern "C" void kernel_launch(void* const* d_in, const int* in_sizes, int n_in,
                              void* d_out, int out_size, void* d_ws, size_t ws_size,
                              hipStream_t stream)
{
    const float* x         = (const float*)d_in[0];
    const int*   y         = (const int*)d_in[1];
    const float* W         = (const float*)d_in[2];
    const float* bias      = (const float*)d_in[3];
    const float* centroid0 = (const float*)d_in[4];

    bf16*  outb  = (bf16*)d_ws;                                // 131072*128 bf16
    float* rnorm = (float*)((char*)d_ws + (size_t)B_ROWS * E_DIM * 2);
    float* pw    = rnorm + B_ROWS;                             // 256*8192
    float* pc    = pw + (long)SEG_BLOCKS * C_CLS * E_DIM;      // 256*64
    float* sums  = pc + SEG_BLOCKS * C_CLS;                    // 8192
    float* cent  = sums + C_CLS * E_DIM;                       // 8192
    float* cnorm = cent + C_CLS * E_DIM;                       // 64

    float* out0  = (float*)d_out;
    float* proto = out0 + (long)B_ROWS * C_CLS;

    gemm_kernel    <<<B_ROWS / BM, 256, 0, stream>>>(x, W, bias, outb, rnorm);
    segsum_kernel  <<<SEG_BLOCKS, 256, 0, stream>>>(outb, y, pw, pc);
    reduce_kernel  <<<(C_CLS * E_DIM) / 256, 256, 0, stream>>>(pw, sums);
    centroid_kernel<<<1, 256, 0, stream>>>(sums, pc, centroid0, cent, cnorm);
    dist_kernel    <<<DIST_BLOCKS + PROTO_BLOCKS, 256, 0, stream>>>(
        outb, cent, cnorm, rnorm, out0, proto);
}